// Round 1
// baseline (851.759 us; speedup 1.0000x reference)
//
#include <hip/hip_runtime.h>
#include <math.h>

#define BB 128
#define T_TOT 1024   // T1*T2 = 128*8
#define DD 1024
#define EE 64

// ---------------------------------------------------------------------------
// Kernel A: partial pooling sums.
// grid = BB * split blocks, 256 threads. Block (b, s) streams rows
// [s*rows, (s+1)*rows) of batch b's [1024 x 1024] slab and accumulates
// per-column sums (thread t owns columns 4t..4t+3 via float4).
// Perfectly coalesced: per iteration the block reads one contiguous 4 KiB row.
// ---------------------------------------------------------------------------
__global__ __launch_bounds__(256) void pool_partial(const float* __restrict__ x,
                                                    float* __restrict__ part,
                                                    int split) {
    const int blk  = blockIdx.x;
    const int b    = blk / split;
    const int s    = blk % split;
    const int rows = T_TOT / split;
    const int t0   = s * rows;
    const int tid  = threadIdx.x;  // 0..255

    const float4* p = (const float4*)(x + ((size_t)b * T_TOT + t0) * DD) + tid;
    float4 acc = make_float4(0.f, 0.f, 0.f, 0.f);
#pragma unroll 4
    for (int t = 0; t < rows; ++t) {
        float4 v = p[(size_t)t * (DD / 4)];
        acc.x += v.x; acc.y += v.y; acc.z += v.z; acc.w += v.w;
    }
    ((float4*)(part + (size_t)blk * DD))[tid] = acc;
}

// ---------------------------------------------------------------------------
// Kernel B: per-row router. One block (256 threads) per batch row b.
//  stage 1: reduce `split` partials -> pooled[1024] in LDS (x 1/1024)
//  stage 2: 4 waves x 16 experts: route & noise dot products (shuffle-reduced)
//  stage 3: wave 0 (lane == expert): softmaxes, softplus-noise, noisy,
//           rank-based top-k (jax.lax.top_k semantics incl. stable ties),
//           the sparse[:,0]=0 padding quirk, final softmax, stores.
// ---------------------------------------------------------------------------
__global__ __launch_bounds__(256) void router_kernel(
    const float* __restrict__ part, int split,
    const float* __restrict__ W_route, const float* __restrict__ b_route,
    const float* __restrict__ W_noise, const float* __restrict__ b_noise,
    const float* __restrict__ noise_eps, const int* __restrict__ mis_mask,
    float* __restrict__ out /* [2*BB*EE]: router_output then noisy */) {
    __shared__ float s_pooled[DD];
    __shared__ float s_route[EE];
    __shared__ float s_noise[EE];

    const int b   = blockIdx.x;
    const int tid = threadIdx.x;

    // ---- stage 1: pooled ----
    {
        float4 acc = make_float4(0.f, 0.f, 0.f, 0.f);
        for (int s = 0; s < split; ++s) {
            float4 v = ((const float4*)(part + (size_t)(b * split + s) * DD))[tid];
            acc.x += v.x; acc.y += v.y; acc.z += v.z; acc.w += v.w;
        }
        const float inv = 1.0f / (float)T_TOT;
        ((float4*)s_pooled)[tid] =
            make_float4(acc.x * inv, acc.y * inv, acc.z * inv, acc.w * inv);
    }
    __syncthreads();

    // ---- stage 2: dots. wave w -> experts [16w, 16w+16) ----
    {
        const int wave = tid >> 6;
        const int lane = tid & 63;
        for (int i = 0; i < 16; ++i) {
            const int e = wave * 16 + i;
            const float* wr = W_route + (size_t)e * DD;
            const float* wn = W_noise + (size_t)e * DD;
            float dr = 0.f, dn = 0.f;
#pragma unroll
            for (int j = 0; j < 16; ++j) {
                const float pv = s_pooled[lane + 64 * j];
                dr += pv * wr[lane + 64 * j];
                dn += pv * wn[lane + 64 * j];
            }
            for (int off = 32; off; off >>= 1) {
                dr += __shfl_down(dr, off, 64);
                dn += __shfl_down(dn, off, 64);
            }
            if (lane == 0) {
                s_route[e] = dr + b_route[e];
                s_noise[e] = dn + b_noise[e];
            }
        }
    }
    __syncthreads();

    // ---- stage 3: wave 0 only (64 lanes = 64 experts) ----
    if (tid < 64) {
        const int e = tid;

        // softmax over route logits
        float x = s_route[e];
        float m = x;
        for (int off = 32; off; off >>= 1) m = fmaxf(m, __shfl_xor(m, off, 64));
        float ex = expf(x - m);
        float sum = ex;
        for (int off = 32; off; off >>= 1) sum += __shfl_xor(sum, off, 64);
        const float p_route = ex / sum;

        // noise path: softmax(noise_eps * softplus(noise_raw))
        const float nr = s_noise[e];
        const float sp = fmaxf(nr, 0.f) + log1pf(expf(-fabsf(nr)));  // stable softplus
        const float h  = noise_eps[b * EE + e] * sp;
        float m2 = h;
        for (int off = 32; off; off >>= 1) m2 = fmaxf(m2, __shfl_xor(m2, off, 64));
        float ex2 = expf(h - m2);
        float sum2 = ex2;
        for (int off = 32; off; off >>= 1) sum2 += __shfl_xor(sum2, off, 64);
        const float p_noise = ex2 / sum2;

        const float noisy = p_route + p_noise;
        out[(size_t)(BB * EE) + b * EE + e] = noisy;  // output 1

        // rank(e) under jax.lax.top_k (descending, stable ties by index)
        const int k = mis_mask[b];
        int cnt = 0;
        for (int j = 0; j < 64; ++j) {
            const float vj = __shfl(noisy, j, 64);
            cnt += (vj > noisy) || (vj == noisy && j < e);
        }
        float sparse = (cnt < k) ? noisy : 0.f;
        // reference quirk: padded rows (k < E) force expert 0's slot to 0
        if (e == 0 && k < EE) sparse = 0.f;

        // final softmax over sparse
        float m3 = sparse;
        for (int off = 32; off; off >>= 1) m3 = fmaxf(m3, __shfl_xor(m3, off, 64));
        float ex3 = expf(sparse - m3);
        float sum3 = ex3;
        for (int off = 32; off; off >>= 1) sum3 += __shfl_xor(sum3, off, 64);
        out[b * EE + e] = ex3 / sum3;  // output 0
    }
}

extern "C" void kernel_launch(void* const* d_in, const int* in_sizes, int n_in,
                              void* d_out, int out_size, void* d_ws, size_t ws_size,
                              hipStream_t stream) {
    const float* mh        = (const float*)d_in[0];  // [128,128,8,1024]
    const float* W_route   = (const float*)d_in[1];  // [64,1024]
    const float* b_route   = (const float*)d_in[2];  // [64]
    const float* W_noise   = (const float*)d_in[3];  // [64,1024]
    const float* b_noise   = (const float*)d_in[4];  // [64]
    const float* noise_eps = (const float*)d_in[5];  // [128,64]
    const int*   mis_mask  = (const int*)d_in[6];    // [128]
    float* out = (float*)d_out;                      // [2*128*64]
    float* ws  = (float*)d_ws;                       // partials [128*split*1024]

    // split=8 needs 4 MiB of workspace; fall back to split=1 (512 KiB) if tight.
    int split = 8;
    if (ws_size < (size_t)BB * 8 * DD * sizeof(float)) split = 1;

    pool_partial<<<BB * split, 256, 0, stream>>>(mh, ws, split);
    router_kernel<<<BB, 256, 0, stream>>>(ws, split, W_route, b_route,
                                          W_noise, b_noise, noise_eps, mis_mask, out);
}

// Round 3
// 685.917 us; speedup vs baseline: 1.2418x; 1.2418x over previous
//
#include <hip/hip_runtime.h>
#include <math.h>

#define BB 128
#define T_TOT 1024   // T1*T2 = 128*8
#define DD 1024
#define EE 64
#define SPLIT 32     // blocks per batch row; partials = BB*SPLIT*DD*4B = 16 MiB

typedef float vfloat4 __attribute__((ext_vector_type(4)));  // native vector for nt builtins

// ---------------------------------------------------------------------------
// Kernel A: partial pooling sums.
// grid = BB*SPLIT blocks x 256 threads. Block (b, s) streams rows
// [s*32, s*32+32) of batch b's [1024 x 1024] slab and accumulates per-column
// sums (thread t owns columns 4t..4t+3 via float4). Per iteration the block
// reads one contiguous 4 KiB row -> fully coalesced. Nontemporal: stream-once
// data, skip L2 retention. 4096 blocks = 16 blocks/CU queue for latency hiding.
// ---------------------------------------------------------------------------
__global__ __launch_bounds__(256) void pool_partial(const float* __restrict__ x,
                                                    float* __restrict__ part) {
    const int blk  = blockIdx.x;
    const int b    = blk / SPLIT;
    const int s    = blk % SPLIT;
    const int rows = T_TOT / SPLIT;  // 32
    const int tid  = threadIdx.x;    // 0..255

    const vfloat4* p =
        (const vfloat4*)(x + ((size_t)b * T_TOT + (size_t)s * rows) * DD) + tid;
    vfloat4 acc = (vfloat4)(0.f);
#pragma unroll 8
    for (int t = 0; t < rows; ++t) {
        vfloat4 v = __builtin_nontemporal_load(&p[(size_t)t * (DD / 4)]);
        acc += v;
    }
    ((vfloat4*)(part + (size_t)blk * DD))[tid] = acc;
}

// ---------------------------------------------------------------------------
// Kernel B: per-row router. One block (256 threads) per batch row b.
//  stage 1: reduce SPLIT partials -> pooled[1024] in LDS (x 1/1024)
//  stage 2: 4 waves x 16 experts: route & noise dot products (shuffle-reduced)
//  stage 3: wave 0 (lane == expert): softmaxes, softplus-noise, noisy,
//           rank-based top-k (jax.lax.top_k semantics incl. stable ties),
//           the sparse[:,0]=0 padding quirk, final softmax, stores.
// ---------------------------------------------------------------------------
__global__ __launch_bounds__(256) void router_kernel(
    const float* __restrict__ part,
    const float* __restrict__ W_route, const float* __restrict__ b_route,
    const float* __restrict__ W_noise, const float* __restrict__ b_noise,
    const float* __restrict__ noise_eps, const int* __restrict__ mis_mask,
    float* __restrict__ out /* [2*BB*EE]: router_output then noisy */) {
    __shared__ float s_pooled[DD];
    __shared__ float s_route[EE];
    __shared__ float s_noise[EE];

    const int b   = blockIdx.x;
    const int tid = threadIdx.x;

    // ---- stage 1: pooled ----
    {
        vfloat4 acc = (vfloat4)(0.f);
#pragma unroll 8
        for (int s = 0; s < SPLIT; ++s) {
            acc += ((const vfloat4*)(part + (size_t)(b * SPLIT + s) * DD))[tid];
        }
        const float inv = 1.0f / (float)T_TOT;
        ((vfloat4*)s_pooled)[tid] = acc * inv;
    }
    __syncthreads();

    // ---- stage 2: dots. wave w -> experts [16w, 16w+16) ----
    {
        const int wave = tid >> 6;
        const int lane = tid & 63;
        for (int i = 0; i < 16; ++i) {
            const int e = wave * 16 + i;
            const float* wr = W_route + (size_t)e * DD;
            const float* wn = W_noise + (size_t)e * DD;
            float dr = 0.f, dn = 0.f;
#pragma unroll
            for (int j = 0; j < 16; ++j) {
                const float pv = s_pooled[lane + 64 * j];
                dr += pv * wr[lane + 64 * j];
                dn += pv * wn[lane + 64 * j];
            }
            for (int off = 32; off; off >>= 1) {
                dr += __shfl_down(dr, off, 64);
                dn += __shfl_down(dn, off, 64);
            }
            if (lane == 0) {
                s_route[e] = dr + b_route[e];
                s_noise[e] = dn + b_noise[e];
            }
        }
    }
    __syncthreads();

    // ---- stage 3: wave 0 only (64 lanes = 64 experts) ----
    if (tid < 64) {
        const int e = tid;

        // softmax over route logits
        float x = s_route[e];
        float m = x;
        for (int off = 32; off; off >>= 1) m = fmaxf(m, __shfl_xor(m, off, 64));
        float ex = expf(x - m);
        float sum = ex;
        for (int off = 32; off; off >>= 1) sum += __shfl_xor(sum, off, 64);
        const float p_route = ex / sum;

        // noise path: softmax(noise_eps * softplus(noise_raw))
        const float nr = s_noise[e];
        const float sp = fmaxf(nr, 0.f) + log1pf(expf(-fabsf(nr)));  // stable softplus
        const float h  = noise_eps[b * EE + e] * sp;
        float m2 = h;
        for (int off = 32; off; off >>= 1) m2 = fmaxf(m2, __shfl_xor(m2, off, 64));
        float ex2 = expf(h - m2);
        float sum2 = ex2;
        for (int off = 32; off; off >>= 1) sum2 += __shfl_xor(sum2, off, 64);
        const float p_noise = ex2 / sum2;

        const float noisy = p_route + p_noise;
        out[(size_t)(BB * EE) + b * EE + e] = noisy;  // output 1

        // rank(e) under jax.lax.top_k (descending, stable ties by index)
        const int k = mis_mask[b];
        int cnt = 0;
        for (int j = 0; j < 64; ++j) {
            const float vj = __shfl(noisy, j, 64);
            cnt += (vj > noisy) || (vj == noisy && j < e);
        }
        float sparse = (cnt < k) ? noisy : 0.f;
        // reference quirk: padded rows (k < E) force expert 0's slot to 0
        if (e == 0 && k < EE) sparse = 0.f;

        // final softmax over sparse
        float m3 = sparse;
        for (int off = 32; off; off >>= 1) m3 = fmaxf(m3, __shfl_xor(m3, off, 64));
        float ex3 = expf(sparse - m3);
        float sum3 = ex3;
        for (int off = 32; off; off >>= 1) sum3 += __shfl_xor(sum3, off, 64);
        out[b * EE + e] = ex3 / sum3;  // output 0
    }
}

extern "C" void kernel_launch(void* const* d_in, const int* in_sizes, int n_in,
                              void* d_out, int out_size, void* d_ws, size_t ws_size,
                              hipStream_t stream) {
    const float* mh        = (const float*)d_in[0];  // [128,128,8,1024]
    const float* W_route   = (const float*)d_in[1];  // [64,1024]
    const float* b_route   = (const float*)d_in[2];  // [64]
    const float* W_noise   = (const float*)d_in[3];  // [64,1024]
    const float* b_noise   = (const float*)d_in[4];  // [64]
    const float* noise_eps = (const float*)d_in[5];  // [128,64]
    const int*   mis_mask  = (const int*)d_in[6];    // [128]
    float* out = (float*)d_out;                      // [2*128*64]
    float* ws  = (float*)d_ws;                       // partials [BB*SPLIT*DD] = 16 MiB

    pool_partial<<<BB * SPLIT, 256, 0, stream>>>(mh, ws);
    router_kernel<<<BB, 256, 0, stream>>>(ws, W_route, b_route,
                                          W_noise, b_noise, noise_eps, mis_mask, out);
}